// Round 7
// baseline (52.827 us; speedup 1.0000x reference)
//
#include <hip/hip_runtime.h>

// KalmanStaticFilter: per-row linear recurrence s_{t+1} = M s_t + c z_t
//   M = [[1-a-b, 1], [-b, 1]], c = [a+b, b], output x_t = p_t + a(z_t - p_t)
// R7: barrier-free, LDS-free. One wave per row; lane-blocked layout (lane
// owns 16 consecutive floats per 1024-elem section; wave span contiguous ->
// L2 merges into full lines). Constant-matrix Kogge-Stone scan over affine
// offsets; per-lane entry via A16^lane; double-buffered register prefetch.

#define A_CONST 0.85f
#define B_CONST 0.005f

constexpr int ROWS = 4096;
constexpr int T    = 8192;
constexpr int L    = 16;         // per-lane chunk length
constexpr int W    = 64 * L;     // 1024 = section width per wave
constexpr int NSEC = T / W;      // 8

__global__ __launch_bounds__(256, 8)
void kalman_kernel(const float* __restrict__ Z, float* __restrict__ X) {
    const int wid  = threadIdx.x >> 6;
    const int lane = threadIdx.x & 63;
    const int row  = (blockIdx.x << 2) | wid;   // 4 independent waves/block

    const float* Zr = Z + (size_t)row * T;
    float*       Xr = X + (size_t)row * T;

    // ---- G[k] = M^(16*2^k), k=0..6 (f64 prologue, folds mostly to SGPR) ----
    double m00 = 1.0 - (double)A_CONST - (double)B_CONST, m01 = 1.0;
    double m10 = -(double)B_CONST,                        m11 = 1.0;
    #pragma unroll
    for (int i = 0; i < 4; ++i) {              // -> M^16
        double n00 = m00*m00 + m01*m10, n01 = m00*m01 + m01*m11;
        double n10 = m10*m00 + m11*m10, n11 = m10*m01 + m11*m11;
        m00 = n00; m01 = n01; m10 = n10; m11 = n11;
    }
    double g00[7], g01[7], g10[7], g11[7];
    g00[0] = m00; g01[0] = m01; g10[0] = m10; g11[0] = m11;
    #pragma unroll
    for (int k = 1; k < 7; ++k) {
        g00[k] = g00[k-1]*g00[k-1] + g01[k-1]*g10[k-1];
        g01[k] = g00[k-1]*g01[k-1] + g01[k-1]*g11[k-1];
        g10[k] = g10[k-1]*g00[k-1] + g11[k-1]*g10[k-1];
        g11[k] = g10[k-1]*g01[k-1] + g11[k-1]*g11[k-1];
    }
    float sc00[6], sc01[6], sc10[6], sc11[6];   // scan-stage A16^(2^k)
    #pragma unroll
    for (int k = 0; k < 6; ++k) {
        sc00[k] = (float)g00[k]; sc01[k] = (float)g01[k];
        sc10[k] = (float)g10[k]; sc11[k] = (float)g11[k];
    }
    const float w00 = (float)g00[6], w01 = (float)g01[6];   // M^1024
    const float w10 = (float)g10[6], w11 = (float)g11[6];

    // per-lane matrix A16^lane via bit product (powers of M commute)
    double l00 = 1.0, l01 = 0.0, l10 = 0.0, l11 = 1.0;
    #pragma unroll
    for (int k = 0; k < 6; ++k) {
        if ((lane >> k) & 1) {
            double n00 = g00[k]*l00 + g01[k]*l10, n01 = g00[k]*l01 + g01[k]*l11;
            double n10 = g10[k]*l00 + g11[k]*l10, n11 = g10[k]*l01 + g11[k]*l11;
            l00 = n00; l01 = n01; l10 = n10; l11 = n11;
        }
    }
    const float La00 = (float)l00, La01 = (float)l01;
    const float La10 = (float)l10, La11 = (float)l11;

    float ps = Zr[0];    // p0 = Z[row][0]
    float vs = 0.0f;

    // double-buffered register prefetch (lane-blocked: 4 float4 = 16 floats)
    float4 rc[4], rn[4];
    {
        const float4* src = (const float4*)(Zr + lane * L);
        #pragma unroll
        for (int i = 0; i < 4; ++i) rc[i] = src[i];
    }

    for (int s = 0; s < NSEC; ++s) {
        // issue next section's loads (in flight under this section's compute)
        if (s + 1 < NSEC) {
            const float4* src = (const float4*)(Zr + (s + 1) * W + lane * L);
            #pragma unroll
            for (int i = 0; i < 4; ++i) rn[i] = src[i];
        }

        // ---- pass A: per-lane chunk offset from s=(0,0) ----
        float bp, bv;
        {
            float p = 0.0f, v = 0.0f;
            #pragma unroll
            for (int i = 0; i < 4; ++i) {
                float zv[4] = { rc[i].x, rc[i].y, rc[i].z, rc[i].w };
                #pragma unroll
                for (int j = 0; j < 4; ++j) {
                    float diff = zv[j] - p;
                    float x    = p + A_CONST * diff;
                    v += B_CONST * diff;
                    p  = x + v;
                }
            }
            bp = p; bv = v;
        }

        // ---- constant-matrix Kogge-Stone scan of offsets ----
        float sb0 = bp, sb1 = bv;
        #pragma unroll
        for (int k = 0; k < 6; ++k) {
            const int d = 1 << k;
            float ob0 = __shfl_up(sb0, d);
            float ob1 = __shfl_up(sb1, d);
            if (lane >= d) {
                sb0 = sc00[k]*ob0 + sc01[k]*ob1 + sb0;
                sb1 = sc10[k]*ob0 + sc11[k]*ob1 + sb1;
            }
        }
        float eb0 = __shfl_up(sb0, 1);
        float eb1 = __shfl_up(sb1, 1);
        if (lane == 0) { eb0 = 0.0f; eb1 = 0.0f; }
        float i0 = __shfl(sb0, 63);
        float i1 = __shfl(sb1, 63);

        // per-lane entry state + next section-start state
        float p   = La00*ps + La01*vs + eb0;
        float v   = La10*ps + La11*vs + eb1;
        float nps = w00*ps + w01*vs + i0;
        float nvs = w10*ps + w11*vs + i1;

        // ---- pass B: replay chunk, overwrite rc with outputs x ----
        #pragma unroll
        for (int i = 0; i < 4; ++i) {
            float zv[4] = { rc[i].x, rc[i].y, rc[i].z, rc[i].w };
            float xv[4];
            #pragma unroll
            for (int j = 0; j < 4; ++j) {
                float diff = zv[j] - p;
                float x    = p + A_CONST * diff;
                v += B_CONST * diff;
                p  = x + v;
                xv[j] = x;
            }
            rc[i] = make_float4(xv[0], xv[1], xv[2], xv[3]);
        }

        // ---- store (lane-blocked, contiguous wave span -> L2 merges) ----
        {
            float4* dst = (float4*)(Xr + s * W + lane * L);
            #pragma unroll
            for (int i = 0; i < 4; ++i) dst[i] = rc[i];
        }

        ps = nps; vs = nvs;
        #pragma unroll
        for (int i = 0; i < 4; ++i) rc[i] = rn[i];
    }
}

extern "C" void kernel_launch(void* const* d_in, const int* in_sizes, int n_in,
                              void* d_out, int out_size, void* d_ws, size_t ws_size,
                              hipStream_t stream) {
    const float* Z = (const float*)d_in[0];
    float*       X = (float*)d_out;
    dim3 grid(ROWS / 4), block(256);
    hipLaunchKernelGGL(kalman_kernel, grid, block, 0, stream, Z, X);
}

// Round 8
// 45.197 us; speedup vs baseline: 1.1688x; 1.1688x over previous
//
#include <hip/hip_runtime.h>

// KalmanStaticFilter: per-row linear recurrence s_{t+1} = M s_t + c z_t
//   M = [[1-a-b, 1], [-b, 1]], c = [a+b, b], output x_t = p_t + a(z_t - p_t)
// R8: BARRIER-FREE single-wave blocks. 64-thread block = 1 wave => no
// __syncthreads needed (intra-wave LDS ordering via compiler lgkmcnt).
// This removes the s_waitcnt vmcnt(0) drain the compiler emits before
// s_barrier, letting the next-section prefetch stay in flight under the
// whole compute phase. Traffic pattern identical to R2/R5 (interleaved
// coalesced loads, LDS chunk-transpose, L=32/STRIDE=33, nt stores).

#define A_CONST 0.85f
#define B_CONST 0.005f

typedef float vfloat4 __attribute__((ext_vector_type(4)));

constexpr int ROWS   = 4096;
constexpr int T      = 8192;
constexpr int W      = 2048;     // section width (one wave)
constexpr int L      = 32;       // per-lane chunk length
constexpr int NSEC   = T / W;    // 4
constexpr int STRIDE = 33;       // padded LDS chunk stride (zero-conflict)

__global__ __launch_bounds__(64)
void kalman_kernel(const float* __restrict__ Z, float* __restrict__ X) {
    const int lane = threadIdx.x;        // 0..63, exactly one wave per block
    const int row  = blockIdx.x;

    __shared__ float buf[64 * STRIDE];   // 8448 B

    const float* Zr = Z + (size_t)row * T;
    float*       Xr = X + (size_t)row * T;

    // ---- f64 precompute: G[k] = M^(32*2^k), k=0..6 ----
    double m00 = 1.0 - (double)A_CONST - (double)B_CONST, m01 = 1.0;
    double m10 = -(double)B_CONST,                        m11 = 1.0;
    #pragma unroll
    for (int i = 0; i < 5; ++i) {          // -> M^32
        double n00 = m00*m00 + m01*m10, n01 = m00*m01 + m01*m11;
        double n10 = m10*m00 + m11*m10, n11 = m10*m01 + m11*m11;
        m00 = n00; m01 = n01; m10 = n10; m11 = n11;
    }
    double g00[7], g01[7], g10[7], g11[7];
    g00[0] = m00; g01[0] = m01; g10[0] = m10; g11[0] = m11;
    #pragma unroll
    for (int k = 1; k < 7; ++k) {
        g00[k] = g00[k-1]*g00[k-1] + g01[k-1]*g10[k-1];
        g01[k] = g00[k-1]*g01[k-1] + g01[k-1]*g11[k-1];
        g10[k] = g10[k-1]*g00[k-1] + g11[k-1]*g10[k-1];
        g11[k] = g10[k-1]*g01[k-1] + g11[k-1]*g11[k-1];
    }
    float sc00[6], sc01[6], sc10[6], sc11[6];   // scan stages A32^(2^k)
    #pragma unroll
    for (int k = 0; k < 6; ++k) {
        sc00[k] = (float)g00[k]; sc01[k] = (float)g01[k];
        sc10[k] = (float)g10[k]; sc11[k] = (float)g11[k];
    }
    const float w00 = (float)g00[6], w01 = (float)g01[6];   // M^2048
    const float w10 = (float)g10[6], w11 = (float)g11[6];

    // per-lane matrix A32^lane via bit product (powers of M commute)
    double l00 = 1.0, l01 = 0.0, l10 = 0.0, l11 = 1.0;
    #pragma unroll
    for (int k = 0; k < 6; ++k) {
        if ((lane >> k) & 1) {
            double n00 = g00[k]*l00 + g01[k]*l10, n01 = g00[k]*l01 + g01[k]*l11;
            double n10 = g10[k]*l00 + g11[k]*l10, n11 = g10[k]*l01 + g11[k]*l11;
            l00 = n00; l01 = n01; l10 = n10; l11 = n11;
        }
    }
    const float La00 = (float)l00, La01 = (float)l01;
    const float La10 = (float)l10, La11 = (float)l11;

    float ps = Zr[0];    // p0 = Z[row][0]
    float vs = 0.0f;

    // prologue: prefetch section 0 (interleaved, coalesced)
    float4 r[8];
    {
        const float4* src = (const float4*)Zr;
        #pragma unroll
        for (int i = 0; i < 8; ++i) r[i] = src[i * 64 + lane];
    }

    for (int s = 0; s < NSEC; ++s) {
        // ---- stage regs into LDS (chunk-transpose); NO barrier after ----
        #pragma unroll
        for (int i = 0; i < 8; ++i) {
            int f = i * 64 + lane;
            int c = f >> 3;                 // chunk
            int j = (f & 7) << 2;           // pos within chunk
            float* p = buf + c * STRIDE + j;
            p[0] = r[i].x; p[1] = r[i].y; p[2] = r[i].z; p[3] = r[i].w;
        }

        // ---- issue next section's loads; they fly under ALL compute below ----
        if (s + 1 < NSEC) {
            const float4* src = (const float4*)(Zr + (s + 1) * W);
            #pragma unroll
            for (int i = 0; i < 8; ++i) r[i] = src[i * 64 + lane];
        }

        // ---- pass A: per-lane chunk offset from s=(0,0); keep z in regs ----
        float c32[L];
        float bp, bv;
        {
            float p = 0.0f, v = 0.0f;
            const float* zc = buf + lane * STRIDE;   // lgkmcnt-ordered vs staging
            #pragma unroll
            for (int j = 0; j < L; ++j) {
                float z    = zc[j];
                c32[j]     = z;
                float diff = z - p;
                float x    = p + A_CONST * diff;
                v += B_CONST * diff;
                p  = x + v;
            }
            bp = p; bv = v;
        }

        // ---- constant-matrix Kogge-Stone scan of offsets ----
        float sb0 = bp, sb1 = bv;
        #pragma unroll
        for (int k = 0; k < 6; ++k) {
            const int d = 1 << k;
            float ob0 = __shfl_up(sb0, d);
            float ob1 = __shfl_up(sb1, d);
            if (lane >= d) {
                sb0 = sc00[k]*ob0 + sc01[k]*ob1 + sb0;
                sb1 = sc10[k]*ob0 + sc11[k]*ob1 + sb1;
            }
        }
        float eb0 = __shfl_up(sb0, 1);
        float eb1 = __shfl_up(sb1, 1);
        if (lane == 0) { eb0 = 0.0f; eb1 = 0.0f; }
        float i0 = __shfl(sb0, 63);
        float i1 = __shfl(sb1, 63);

        // per-lane entry state + next section-start state
        float p   = La00*ps + La01*vs + eb0;
        float v   = La10*ps + La11*vs + eb1;
        float nps = w00*ps + w01*vs + i0;
        float nvs = w10*ps + w11*vs + i1;

        // ---- pass B: replay chunk from regs, write x to LDS ----
        {
            float* zc = buf + lane * STRIDE;
            #pragma unroll
            for (int j = 0; j < L; ++j) {
                float z    = c32[j];
                float diff = z - p;
                float x    = p + A_CONST * diff;
                v += B_CONST * diff;
                p  = x + v;
                zc[j] = x;
            }
        }

        // ---- unload: transposed read from LDS, coalesced nt stores ----
        {
            vfloat4* dst = (vfloat4*)(Xr + s * W);
            #pragma unroll
            for (int i = 0; i < 8; ++i) {
                int f = i * 64 + lane;
                int c = f >> 3;
                int j = (f & 7) << 2;
                const float* q = buf + c * STRIDE + j;
                vfloat4 v4 = { q[0], q[1], q[2], q[3] };
                __builtin_nontemporal_store(v4, dst + f);
            }
        }

        ps = nps; vs = nvs;
        // next iteration's staging overwrites buf: WAR vs this unload's
        // ds_reads is ordered by in-wave lgkmcnt — no barrier needed.
    }
}

extern "C" void kernel_launch(void* const* d_in, const int* in_sizes, int n_in,
                              void* d_out, int out_size, void* d_ws, size_t ws_size,
                              hipStream_t stream) {
    const float* Z = (const float*)d_in[0];
    float*       X = (float*)d_out;
    dim3 grid(ROWS), block(64);
    hipLaunchKernelGGL(kalman_kernel, grid, block, 0, stream, Z, X);
}